// Round 7
// baseline (486.483 us; speedup 1.0000x reference)
//
#include <hip/hip_runtime.h>

// OT_GNN: 2x GCN -> per-node fused-GW distance to 10 templates -> linear head.
// R7: gemm1 MFMA kept, but W1 is pre-swizzled ONCE into global ws in B-frag
// lane order (wswz_kernel). gemm1 has no LDS/barrier: A-frags prefetched to
// registers, B-frags are coalesced L2-hot loads. (R6's per-block 64KB LDS
// staging serialized the kernel at 313 blocks.)
// Certificate (R4): K = exp(-5(M+tens)) == 0 exactly in fp32 when
// (sqrt(tn2min)-sqrt(xn2max))^2 >= 26, since tens >= -2 => dist == 0 exact.

#define NN   20000
#define EE   320000
#define FIN  512
#define HID  64
#define KNEI 8
#define LSZ  9      // K_NEI + 1
#define NTPL 10
#define NTN  8
#define NCLS 6
#define CAP  48     // bucket capacity per node (max in-degree ~34)

typedef unsigned short bf16_t;
typedef short s16x8 __attribute__((ext_vector_type(8)));
typedef float f32x4 __attribute__((ext_vector_type(4)));

__device__ __forceinline__ float b2f(bf16_t u) {
  union { unsigned int i; float f; } v; v.i = ((unsigned int)u) << 16; return v.f;
}
__device__ __forceinline__ bf16_t f2b(float f) {
  union { float f; unsigned int i; } v; v.f = f;
  unsigned int x = v.i;
  return (bf16_t)((x + 0x7fffu + ((x >> 16) & 1u)) >> 16);  // RNE
}
__device__ __forceinline__ float ldf(const void* p, long i, int fp32) {
  return fp32 ? ((const float*)p)[i] : b2f(((const bf16_t*)p)[i]);
}
__device__ __forceinline__ int ldi(const void* p, long i, int i64) {
  return i64 ? (int)((const long long*)p)[i] : ((const int*)p)[i];
}
__device__ __forceinline__ float frcp(float x) { return __builtin_amdgcn_rcpf(x); }

// ---------- dtype probe + template row-norm mins ----------
__global__ __launch_bounds__(128) void probe_kernel(const void* __restrict__ x,
                                                    const void* __restrict__ ei,
                                                    const void* __restrict__ tfeat,
                                                    int* __restrict__ flags,
                                                    float* __restrict__ tn2min) {
  __shared__ int sfl[2];
  __shared__ float tn2s[80];
  int tid = threadIdx.x;
  if (tid == 0) {
    int sane = 0;
    for (int k = 0; k < 64; k += 2) {
      bf16_t u = ((const bf16_t*)x)[k];
      int e = (u >> 7) & 0xff;
      if (e >= 112 && e <= 142) sane++;
    }
    int f0 = (sane < 24) ? 1 : 0;
    int zc = 0;
    for (int k = 1; k < 64; k += 2)
      if (((const int*)ei)[k] == 0) zc++;
    int f1 = (zc >= 16) ? 1 : 0;
    flags[0] = f0; flags[1] = f1;
    sfl[0] = f0; sfl[1] = f1;
  }
  __syncthreads();
  if (tid < 80) {
    int fF = sfl[0];
    float s = 0.f;
    for (int k = 0; k < HID; ++k) {
      float v = ldf(tfeat, (long)tid * HID + k, fF);
      s += v * v;
    }
    tn2s[tid] = s;
  }
  __syncthreads();
  if (tid == 0) {
    float gmin = 1e30f;
    for (int t = 0; t < NTPL; ++t) {
      float m = tn2s[t * 8];
      for (int r = 1; r < 8; ++r) m = fminf(m, tn2s[t * 8 + r]);
      tn2min[t] = m;
      gmin = fminf(gmin, m);
    }
    tn2min[NTPL] = gmin;
  }
}

// ---------- W1 pre-swizzle into B-fragment lane order ----------
// Wp[(kk*4+nt)*64 + lane] (s16x8), element j = W1[k*HID+n],
// k = kk*32 + (lane>>4)*8 + j, n = nt*16 + (lane&15).
__global__ __launch_bounds__(256) void wswz_kernel(const void* __restrict__ W1,
                                                   bf16_t* __restrict__ Wp,
                                                   const int* __restrict__ flags) {
  if (flags[0]) return;   // fp32 flavor: gemm1 fallback reads W1 directly
  int idx = blockIdx.x * 256 + threadIdx.x;   // 0..32767
  int j = idx & 7;
  int lane = (idx >> 3) & 63;
  int nt = (idx >> 9) & 3;
  int kk = idx >> 11;
  int k = kk * 32 + (lane >> 4) * 8 + j;
  int n = nt * 16 + (lane & 15);
  Wp[idx] = ((const bf16_t*)W1)[k * HID + n];
}

// ---------- bucket scatter: pos becomes in-degree, slot holds sources -------
__global__ __launch_bounds__(256) void scatter_kernel(const void* __restrict__ ei,
                                                      int* __restrict__ pos,
                                                      int* __restrict__ slot,
                                                      const int* __restrict__ flags) {
  int i = blockIdx.x * 256 + threadIdx.x;
  if (i >= EE) return;
  int i64 = flags[1];
  int s = ldi(ei, i, i64);
  int d = ldi(ei, (long)EE + i, i64);
  int p = atomicAdd(&pos[d], 1);
  if (p < CAP) slot[d * CAP + p] = s;
}
__global__ __launch_bounds__(256) void dinv_kernel(const int* __restrict__ cnt,
                                                   float* __restrict__ dinv) {
  int i = blockIdx.x * 256 + threadIdx.x;
  if (i < NN) dinv[i] = rsqrtf((float)cnt[i] + 1.0f);   // +1 self loop
}

// ---------- GEMM1 via MFMA, no LDS: xw1 = x @ W1 ----------
__global__ __launch_bounds__(256) void gemm1_kernel(const void* __restrict__ x,
                                                    const bf16_t* __restrict__ Wp,
                                                    const void* __restrict__ W1,
                                                    float* __restrict__ xw1,
                                                    const int* __restrict__ flags) {
  const int tid = threadIdx.x;
  const int wid = blockIdx.x * 4 + (tid >> 6);
  const int lane = tid & 63;
  if (wid >= NN / 16) return;
  const int row0 = wid * 16;
  if (!flags[0]) {
    // A-frag: A[m][k], m=lane&15, k=(lane>>4)*8 + j (+32 per kk step)
    const bf16_t* xr = (const bf16_t*)x + (long)(row0 + (lane & 15)) * FIN
                       + (lane >> 4) * 8;
    s16x8 a[16];
#pragma unroll
    for (int kk = 0; kk < 16; ++kk) a[kk] = *(const s16x8*)(xr + kk * 32);
    const s16x8* wp = (const s16x8*)Wp;
    f32x4 acc0 = {0.f, 0.f, 0.f, 0.f}, acc1 = acc0, acc2 = acc0, acc3 = acc0;
#pragma unroll
    for (int kk = 0; kk < 16; ++kk) {
      s16x8 b0 = wp[(kk * 4 + 0) * 64 + lane];
      s16x8 b1 = wp[(kk * 4 + 1) * 64 + lane];
      s16x8 b2 = wp[(kk * 4 + 2) * 64 + lane];
      s16x8 b3 = wp[(kk * 4 + 3) * 64 + lane];
      acc0 = __builtin_amdgcn_mfma_f32_16x16x32_bf16(a[kk], b0, acc0, 0, 0, 0);
      acc1 = __builtin_amdgcn_mfma_f32_16x16x32_bf16(a[kk], b1, acc1, 0, 0, 0);
      acc2 = __builtin_amdgcn_mfma_f32_16x16x32_bf16(a[kk], b2, acc2, 0, 0, 0);
      acc3 = __builtin_amdgcn_mfma_f32_16x16x32_bf16(a[kk], b3, acc3, 0, 0, 0);
    }
    // C/D: col = lane&15, row = (lane>>4)*4 + reg
    const int rbase = row0 + (lane >> 4) * 4;
    const int c = lane & 15;
#pragma unroll
    for (int r = 0; r < 4; ++r) {
      float* o = xw1 + (long)(rbase + r) * HID + c;
      o[0]  = acc0[r];
      o[16] = acc1[r];
      o[32] = acc2[r];
      o[48] = acc3[r];
    }
  } else {
    // fp32 fallback
    const float* wp = (const float*)W1;
    for (int r = 0; r < 16; ++r) {
      const float* x0 = (const float*)x + (long)(row0 + r) * FIN;
      float a = 0.f;
      for (int k = 0; k < FIN; ++k) a += x0[k] * wp[k * HID + lane];
      xw1[(long)(row0 + r) * HID + lane] = a;
    }
  }
}

// ---------- GEMM2: xw2 = h1 @ W2 (float4 h loads) ----------
__global__ __launch_bounds__(256) void gemm2_kernel(const float* __restrict__ h,
                                                    const void* __restrict__ W2,
                                                    float* __restrict__ xw2,
                                                    const int* __restrict__ flags) {
  int wave = blockIdx.x * 4 + (threadIdx.x >> 6);
  int lane = threadIdx.x & 63;
  int row0 = wave * 4;
  if (row0 >= NN) return;
  int fF = flags[0];
  float a0 = 0.f, a1 = 0.f, a2 = 0.f, a3 = 0.f;
  const float* h0 = h + (long)row0 * HID;
#pragma unroll 4
  for (int k4 = 0; k4 < HID / 4; ++k4) {
    float4 r0 = *(const float4*)(h0 + k4 * 4);
    float4 r1 = *(const float4*)(h0 + HID + k4 * 4);
    float4 r2 = *(const float4*)(h0 + 2 * HID + k4 * 4);
    float4 r3 = *(const float4*)(h0 + 3 * HID + k4 * 4);
#pragma unroll
    for (int q = 0; q < 4; ++q) {
      float w = ldf(W2, (k4 * 4 + q) * HID + lane, fF);
      float e0 = (q == 0) ? r0.x : (q == 1) ? r0.y : (q == 2) ? r0.z : r0.w;
      float e1 = (q == 0) ? r1.x : (q == 1) ? r1.y : (q == 2) ? r1.z : r1.w;
      float e2 = (q == 0) ? r2.x : (q == 1) ? r2.y : (q == 2) ? r2.z : r2.w;
      float e3 = (q == 0) ? r3.x : (q == 1) ? r3.y : (q == 2) ? r3.z : r3.w;
      a0 += e0 * w; a1 += e1 * w; a2 += e2 * w; a3 += e3 * w;
    }
  }
  xw2[(long)(row0 + 0) * HID + lane] = a0;
  xw2[(long)(row0 + 1) * HID + lane] = a1;
  xw2[(long)(row0 + 2) * HID + lane] = a2;
  xw2[(long)(row0 + 3) * HID + lane] = a3;
}

// ---------- GCN aggregation via bucket gather ----------
__global__ __launch_bounds__(256) void gather_kernel(const float* __restrict__ xw,
                                                     const float* __restrict__ dinv,
                                                     const int* __restrict__ cnt,
                                                     const int* __restrict__ slot,
                                                     float* __restrict__ h,
                                                     float* __restrict__ n2,
                                                     const void* __restrict__ bias,
                                                     const int* __restrict__ flags,
                                                     int mode) {
  int n = blockIdx.x * 4 + (threadIdx.x >> 6);
  if (n >= NN) return;
  int c = threadIdx.x & 63;
  float dn = dinv[n];
  float acc = xw[(long)n * HID + c] * dn;      // self term
  int m = cnt[n]; if (m > CAP) m = CAP;
  const int* sl = slot + (long)n * CAP;
  for (int e0 = 0; e0 < m; e0 += 4) {
    int4 s4 = *(const int4*)(sl + e0);
    if (e0 + 0 < m) acc += xw[(long)s4.x * HID + c] * dinv[s4.x];
    if (e0 + 1 < m) acc += xw[(long)s4.y * HID + c] * dinv[s4.y];
    if (e0 + 2 < m) acc += xw[(long)s4.z * HID + c] * dinv[s4.z];
    if (e0 + 3 < m) acc += xw[(long)s4.w * HID + c] * dinv[s4.w];
  }
  acc *= dn;
  float b = ldf(bias, c, flags[0]);
  if (mode) {
    acc += b;
    acc = acc > 0.f ? acc : 0.f;
    h[(long)n * HID + c] = acc;
  } else {
    h[(long)n * HID + c] = acc;
    float v = acc + b;
    float s = v * v;
    s += __shfl_xor(s, 1); s += __shfl_xor(s, 2); s += __shfl_xor(s, 4);
    s += __shfl_xor(s, 8); s += __shfl_xor(s, 16); s += __shfl_xor(s, 32);
    if (c == 0) n2[n] = s;
  }
}

// ---------- FGW: 4 nodes/block, 8-lane octet per (node, template) ----------
#define NODES_PB 4
#define TPN 80            // threads per node (10 templates x 8 lanes)
#define XLP 65            // padded xl row stride

__global__ __launch_bounds__(320, 2) void fgw_kernel(
    const float* __restrict__ h2,        // [NN,64] fp32 ws (pre-b2)
    const void* __restrict__ b2v,
    const void* __restrict__ nbr_idx,
    const void* __restrict__ nbr_mask,
    const void* __restrict__ C_local,
    const void* __restrict__ tmpl,       // [10,8,8]
    const void* __restrict__ tfeat,      // [10,8,64]
    const void* __restrict__ Wlin,       // [74,6]
    const void* __restrict__ blin,       // [6]
    void* __restrict__ out,              // [NN,6]
    const int* __restrict__ flags,
    const float* __restrict__ tn2min,    // [11]: per-t mins + global min
    const float* __restrict__ n2)        // [NN] node norm^2
{
  const int tid = threadIdx.x;
  const int fF = flags[0];
  const int fI = flags[1];
  const int nb = tid / TPN;
  const int local = tid - nb * TPN;      // [0,80)
  const int t = local >> 3;
  const int j = local & 7;
  const int n = blockIdx.x * NODES_PB + nb;
  const int lane = tid & 63;
  const int ob = lane & 56;

  __shared__ float xlS[NODES_PB][LSZ][XLP];
  __shared__ float C1S[NODES_PB][81];
  __shared__ float hwS[NODES_PB][LSZ];
  __shared__ float f1S[NODES_PB][LSZ];
  __shared__ float xnS[NODES_PB][LSZ];
  __shared__ float distS[NODES_PB][NTPL];
  __shared__ float xmaxS[NODES_PB];
  __shared__ int   needS[NODES_PB];
  __shared__ int   sidxS[NODES_PB][LSZ];

  if (local < LSZ) {
    int idx = (local == 0) ? n : ldi(nbr_idx, (long)n * KNEI + local - 1, fI);
    sidxS[nb][local] = idx;
    xnS[nb][local] = n2[idx];
  }
  if (local < HID)
    xlS[nb][0][local] = h2[(long)n * HID + local] + ldf(b2v, local, fF);
  __syncthreads();   // B1

  if (local == 0) {
    float xm = xnS[nb][0];
#pragma unroll
    for (int l = 1; l < LSZ; ++l) xm = fmaxf(xm, xnS[nb][l]);
    xmaxS[nb] = xm;
    needS[nb] = ((sqrtf(tn2min[NTPL]) - sqrtf(xm)) >= 5.0990195f) ? 0 : 1;
  }
  __syncthreads();   // B2

  const int need = needS[nb];
  if (need) {
    for (int i = local; i < 8 * HID; i += TPN) {
      int l = 1 + (i >> 6), k = i & 63;
      xlS[nb][l][k] = h2[(long)sidxS[nb][l] * HID + k] + ldf(b2v, k, fF);
    }
    for (int i = local; i < 81; i += TPN)
      C1S[nb][i] = ldf(C_local, (long)n * 81 + i, fF);
  }
  __syncthreads();   // B3

  if (need && local < LSZ) {
    int l = local;
    float msum = 0.f, f1 = 0.f;
#pragma unroll
    for (int jj = 0; jj < LSZ; ++jj) {
      float mj = ldf(nbr_mask, (long)n * LSZ + jj, fF);
      msum += mj;
      float c = C1S[nb][l * LSZ + jj];
      f1 += c * c * mj;
    }
    float inv = frcp(msum);
    hwS[nb][l] = ldf(nbr_mask, (long)n * LSZ + l, fF) * inv;
    f1S[nb][l] = f1 * inv;
  }
  __syncthreads();   // B4

  bool slow = need && ((sqrtf(tn2min[t]) - sqrtf(xmaxS[nb])) < 5.0990195f);
  if (slow) {
    float C2c[NTN];
    float f2h2;
    {
      float s = 0.f;
#pragma unroll
      for (int m = 0; m < NTN; ++m) {
        C2c[m] = ldf(tmpl, t * 64 + m * 8 + j, fF);
        float r = ldf(tmpl, t * 64 + j * 8 + m, fF);
        s += r * r;
      }
      f2h2 = s * 0.125f;
    }
    float hwr[LSZ], f1r[LSZ];
#pragma unroll
    for (int l = 0; l < LSZ; ++l) { hwr[l] = hwS[nb][l]; f1r[l] = f1S[nb][l]; }

    float Mc[LSZ];
    {
      float accI[LSZ];
#pragma unroll
      for (int l = 0; l < LSZ; ++l) accI[l] = 0.f;
      float tn2 = 0.f;
      const long tb = (long)local * HID;
      for (int kb = 0; kb < 8; ++kb) {
        float r[8];
#pragma unroll
        for (int q = 0; q < 8; ++q) r[q] = ldf(tfeat, tb + kb * 8 + q, fF);
#pragma unroll
        for (int q = 0; q < 8; ++q) tn2 += r[q] * r[q];
#pragma unroll
        for (int l = 0; l < LSZ; ++l) {
          float s = 0.f;
#pragma unroll
          for (int q = 0; q < 8; ++q) s += xlS[nb][l][kb * 8 + q] * r[q];
          accI[l] += s;
        }
      }
#pragma unroll
      for (int l = 0; l < LSZ; ++l)
        Mc[l] = xnS[nb][l] + tn2 - 2.f * accI[l];
    }

    float Tc[LSZ], Kc[LSZ], u[LSZ];
#pragma unroll
    for (int l = 0; l < LSZ; ++l) Tc[l] = hwr[l] * 0.125f;

    float v = 1.0f;
    for (int outer = 0; outer < 3; ++outer) {
      float Ac[LSZ];
#pragma unroll
      for (int l = 0; l < LSZ; ++l) {
        float s = 0.f;
#pragma unroll
        for (int l2 = 0; l2 < LSZ; ++l2) s += C1S[nb][l * LSZ + l2] * Tc[l2];
        Ac[l] = s;
      }
#pragma unroll
      for (int l = 0; l < LSZ; ++l) {
        float s = 0.f;
#pragma unroll
        for (int m = 0; m < NTN; ++m) s += __shfl(Ac[l], ob + m) * C2c[m];
        float tens = f1r[l] + f2h2 - 2.f * s;
        Kc[l] = __expf(-5.0f * (Mc[l] + tens));
      }
      v = 1.0f;
      for (int it = 0; it < 5; ++it) {
#pragma unroll
        for (int l = 0; l < LSZ; ++l) {
          float p = Kc[l] * v;
          p += __shfl_xor(p, 1); p += __shfl_xor(p, 2); p += __shfl_xor(p, 4);
          u[l] = hwr[l] * frcp(p + 1e-16f);
        }
        float s = 0.f;
#pragma unroll
        for (int l = 0; l < LSZ; ++l) s += Kc[l] * u[l];
        v = 0.125f * frcp(s + 1e-16f);
      }
#pragma unroll
      for (int l = 0; l < LSZ; ++l) Tc[l] = u[l] * Kc[l] * v;
    }
    {
      float Ac[LSZ];
#pragma unroll
      for (int l = 0; l < LSZ; ++l) {
        float s = 0.f;
#pragma unroll
        for (int l2 = 0; l2 < LSZ; ++l2) s += C1S[nb][l * LSZ + l2] * Tc[l2];
        Ac[l] = s;
      }
      float cl = 0.f;
#pragma unroll
      for (int l = 0; l < LSZ; ++l) {
        float s = 0.f;
#pragma unroll
        for (int m = 0; m < NTN; ++m) s += __shfl(Ac[l], ob + m) * C2c[m];
        float tens = f1r[l] + f2h2 - 2.f * s;
        cl += Tc[l] * 0.5f * (Mc[l] + tens);
      }
      cl += __shfl_xor(cl, 1); cl += __shfl_xor(cl, 2); cl += __shfl_xor(cl, 4);
      if (j == 0) distS[nb][t] = cl;
    }
  } else if (j == 0) {
    distS[nb][t] = 0.f;
  }
  __syncthreads();   // B5

  if (local < NCLS) {
    int c = local;
    float acc = ldf(blin, c, fF);
#pragma unroll
    for (int k = 0; k < HID; ++k)
      acc += xlS[nb][0][k] * ldf(Wlin, k * NCLS + c, fF);
#pragma unroll
    for (int tt = 0; tt < NTPL; ++tt)
      acc += distS[nb][tt] * ldf(Wlin, (HID + tt) * NCLS + c, fF);
    float r = acc > 0.f ? acc : 0.f;
    if (fF) ((float*)out)[(long)n * NCLS + c] = r;
    else    ((bf16_t*)out)[(long)n * NCLS + c] = f2b(r);
  }
}

extern "C" void kernel_launch(void* const* d_in, const int* in_sizes, int n_in,
                              void* d_out, int out_size, void* d_ws, size_t ws_size,
                              hipStream_t stream) {
  (void)in_sizes; (void)n_in; (void)out_size; (void)ws_size;
  const void* x     = d_in[0];
  const void* ei    = d_in[1];
  const void* nbr   = d_in[2];
  const void* nmask = d_in[3];
  const void* Cl    = d_in[4];
  const void* W1    = d_in[5];
  const void* b1    = d_in[6];
  const void* W2    = d_in[7];
  const void* b2    = d_in[8];
  const void* tmpl  = d_in[9];
  const void* tfeat = d_in[10];
  const void* Wlin  = d_in[11];
  const void* blin  = d_in[12];

  // ws layout (4B words): flags[4] | tn2min[12] | dinv NN | n2 NN | pos NN |
  //                       slot CAP*NN | Wp 16K words (64KB) | bufA 64NN | bufB 64NN
  int*    flags  = (int*)d_ws;
  float*  tn2min = (float*)d_ws + 4;
  float*  dinv   = (float*)d_ws + 16;
  float*  n2     = dinv + NN;
  int*    pos    = (int*)(n2 + NN);
  int*    slot   = pos + NN;
  bf16_t* Wp     = (bf16_t*)(slot + (long)CAP * NN);
  float*  bufA   = (float*)((int*)Wp + 16384);
  float*  bufB   = bufA + (long)NN * HID;

  probe_kernel<<<1, 128, 0, stream>>>(x, ei, tfeat, flags, tn2min);
  wswz_kernel<<<128, 256, 0, stream>>>(W1, Wp, flags);

  hipMemsetAsync(pos, 0, NN * sizeof(int), stream);
  scatter_kernel<<<(EE + 255) / 256, 256, 0, stream>>>(ei, pos, slot, flags);
  dinv_kernel<<<(NN + 255) / 256, 256, 0, stream>>>(pos, dinv);

  // layer 1
  gemm1_kernel<<<(NN / 16 + 3) / 4, 256, 0, stream>>>(x, Wp, W1, bufA, flags);
  gather_kernel<<<NN / 4, 256, 0, stream>>>(bufA, dinv, pos, slot, bufB,
                                            n2, b1, flags, 1);
  // layer 2 (n2 fused into this gather)
  gemm2_kernel<<<NN / 16, 256, 0, stream>>>(bufB, W2, bufA, flags);
  gather_kernel<<<NN / 4, 256, 0, stream>>>(bufA, dinv, pos, slot, bufB,
                                            n2, b2, flags, 0);

  fgw_kernel<<<NN / NODES_PB, 320, 0, stream>>>(bufB, b2, nbr, nmask, Cl, tmpl,
                                                tfeat, Wlin, blin, d_out, flags,
                                                tn2min, n2);
}

// Round 8
// 393.250 us; speedup vs baseline: 1.2371x; 1.2371x over previous
//
#include <hip/hip_runtime.h>

// OT_GNN: 2x GCN -> per-node fused-GW distance to 10 templates -> linear head.
// R8: gemm1 MFMA re-gridded for latency hiding: 1250 blocks x 4 waves, one
// 16-col n-tile per wave (5000 waves vs R7's 1252). Block's 4 waves share the
// same A rows (L1 reuse); per-wave ops cut 4x. W1 pre-swizzle (R7) retained.
// Certificate (R4): K = exp(-5(M+tens)) == 0 exactly in fp32 when
// (sqrt(tn2min)-sqrt(xn2max))^2 >= 26, since tens >= -2 => dist == 0 exact.

#define NN   20000
#define EE   320000
#define FIN  512
#define HID  64
#define KNEI 8
#define LSZ  9      // K_NEI + 1
#define NTPL 10
#define NTN  8
#define NCLS 6
#define CAP  48     // bucket capacity per node (max in-degree ~34)

typedef unsigned short bf16_t;
typedef short s16x8 __attribute__((ext_vector_type(8)));
typedef float f32x4 __attribute__((ext_vector_type(4)));

__device__ __forceinline__ float b2f(bf16_t u) {
  union { unsigned int i; float f; } v; v.i = ((unsigned int)u) << 16; return v.f;
}
__device__ __forceinline__ bf16_t f2b(float f) {
  union { float f; unsigned int i; } v; v.f = f;
  unsigned int x = v.i;
  return (bf16_t)((x + 0x7fffu + ((x >> 16) & 1u)) >> 16);  // RNE
}
__device__ __forceinline__ float ldf(const void* p, long i, int fp32) {
  return fp32 ? ((const float*)p)[i] : b2f(((const bf16_t*)p)[i]);
}
__device__ __forceinline__ int ldi(const void* p, long i, int i64) {
  return i64 ? (int)((const long long*)p)[i] : ((const int*)p)[i];
}
__device__ __forceinline__ float frcp(float x) { return __builtin_amdgcn_rcpf(x); }

// ---------- dtype probe + template row-norm mins ----------
__global__ __launch_bounds__(128) void probe_kernel(const void* __restrict__ x,
                                                    const void* __restrict__ ei,
                                                    const void* __restrict__ tfeat,
                                                    int* __restrict__ flags,
                                                    float* __restrict__ tn2min) {
  __shared__ int sfl[2];
  __shared__ float tn2s[80];
  int tid = threadIdx.x;
  if (tid == 0) {
    int sane = 0;
    for (int k = 0; k < 64; k += 2) {
      bf16_t u = ((const bf16_t*)x)[k];
      int e = (u >> 7) & 0xff;
      if (e >= 112 && e <= 142) sane++;
    }
    int f0 = (sane < 24) ? 1 : 0;
    int zc = 0;
    for (int k = 1; k < 64; k += 2)
      if (((const int*)ei)[k] == 0) zc++;
    int f1 = (zc >= 16) ? 1 : 0;
    flags[0] = f0; flags[1] = f1;
    sfl[0] = f0; sfl[1] = f1;
  }
  __syncthreads();
  if (tid < 80) {
    int fF = sfl[0];
    float s = 0.f;
    for (int k = 0; k < HID; ++k) {
      float v = ldf(tfeat, (long)tid * HID + k, fF);
      s += v * v;
    }
    tn2s[tid] = s;
  }
  __syncthreads();
  if (tid == 0) {
    float gmin = 1e30f;
    for (int t = 0; t < NTPL; ++t) {
      float m = tn2s[t * 8];
      for (int r = 1; r < 8; ++r) m = fminf(m, tn2s[t * 8 + r]);
      tn2min[t] = m;
      gmin = fminf(gmin, m);
    }
    tn2min[NTPL] = gmin;
  }
}

// ---------- W1 pre-swizzle into B-fragment lane order ----------
// Wp[(kk*4+nt)*64 + lane] (s16x8), element j = W1[k*HID+n],
// k = kk*32 + (lane>>4)*8 + j, n = nt*16 + (lane&15).
__global__ __launch_bounds__(256) void wswz_kernel(const void* __restrict__ W1,
                                                   bf16_t* __restrict__ Wp,
                                                   const int* __restrict__ flags) {
  if (flags[0]) return;
  int idx = blockIdx.x * 256 + threadIdx.x;   // 0..32767
  int j = idx & 7;
  int lane = (idx >> 3) & 63;
  int nt = (idx >> 9) & 3;
  int kk = idx >> 11;
  int k = kk * 32 + (lane >> 4) * 8 + j;
  int n = nt * 16 + (lane & 15);
  Wp[idx] = ((const bf16_t*)W1)[k * HID + n];
}

// ---------- bucket scatter ----------
__global__ __launch_bounds__(256) void scatter_kernel(const void* __restrict__ ei,
                                                      int* __restrict__ pos,
                                                      int* __restrict__ slot,
                                                      const int* __restrict__ flags) {
  int i = blockIdx.x * 256 + threadIdx.x;
  if (i >= EE) return;
  int i64 = flags[1];
  int s = ldi(ei, i, i64);
  int d = ldi(ei, (long)EE + i, i64);
  int p = atomicAdd(&pos[d], 1);
  if (p < CAP) slot[d * CAP + p] = s;
}
__global__ __launch_bounds__(256) void dinv_kernel(const int* __restrict__ cnt,
                                                   float* __restrict__ dinv) {
  int i = blockIdx.x * 256 + threadIdx.x;
  if (i < NN) dinv[i] = rsqrtf((float)cnt[i] + 1.0f);   // +1 self loop
}

// ---------- GEMM1 via MFMA: 1250 blocks x 4 waves, one n-tile per wave ------
__global__ __launch_bounds__(256) void gemm1_kernel(const void* __restrict__ x,
                                                    const bf16_t* __restrict__ Wp,
                                                    const void* __restrict__ W1,
                                                    float* __restrict__ xw1,
                                                    const int* __restrict__ flags) {
  const int tid = threadIdx.x;
  const int nt = tid >> 6;           // n-tile owned by this wave
  const int lane = tid & 63;
  const int row0 = blockIdx.x * 16;
  if (!flags[0]) {
    // A-frag: A[m][k], m=lane&15, k=(lane>>4)*8 + j (+32 per kk step)
    const bf16_t* xr = (const bf16_t*)x + (long)(row0 + (lane & 15)) * FIN
                       + (lane >> 4) * 8;
    const s16x8* wp = (const s16x8*)Wp + nt * 64 + lane;
    f32x4 acc = {0.f, 0.f, 0.f, 0.f};
#pragma unroll
    for (int kk = 0; kk < 16; ++kk) {
      s16x8 a = *(const s16x8*)(xr + kk * 32);
      s16x8 b = wp[kk * 256];
      acc = __builtin_amdgcn_mfma_f32_16x16x32_bf16(a, b, acc, 0, 0, 0);
    }
    // C/D: col = lane&15 (+nt*16), row = (lane>>4)*4 + reg
    const int rbase = row0 + (lane >> 4) * 4;
    const int c = nt * 16 + (lane & 15);
#pragma unroll
    for (int r = 0; r < 4; ++r)
      xw1[(long)(rbase + r) * HID + c] = acc[r];
  } else {
    // fp32 fallback: 4 rows per wave via nt
    const float* wp = (const float*)W1;
    for (int r = nt * 4; r < nt * 4 + 4; ++r) {
      const float* x0 = (const float*)x + (long)(row0 + r) * FIN;
      float a = 0.f;
      for (int k = 0; k < FIN; ++k) a += x0[k] * wp[k * HID + lane];
      xw1[(long)(row0 + r) * HID + lane] = a;
    }
  }
}

// ---------- GEMM2: xw2 = h1 @ W2 (float4 h loads) ----------
__global__ __launch_bounds__(256) void gemm2_kernel(const float* __restrict__ h,
                                                    const void* __restrict__ W2,
                                                    float* __restrict__ xw2,
                                                    const int* __restrict__ flags) {
  int wave = blockIdx.x * 4 + (threadIdx.x >> 6);
  int lane = threadIdx.x & 63;
  int row0 = wave * 4;
  if (row0 >= NN) return;
  int fF = flags[0];
  float a0 = 0.f, a1 = 0.f, a2 = 0.f, a3 = 0.f;
  const float* h0 = h + (long)row0 * HID;
#pragma unroll 4
  for (int k4 = 0; k4 < HID / 4; ++k4) {
    float4 r0 = *(const float4*)(h0 + k4 * 4);
    float4 r1 = *(const float4*)(h0 + HID + k4 * 4);
    float4 r2 = *(const float4*)(h0 + 2 * HID + k4 * 4);
    float4 r3 = *(const float4*)(h0 + 3 * HID + k4 * 4);
#pragma unroll
    for (int q = 0; q < 4; ++q) {
      float w = ldf(W2, (k4 * 4 + q) * HID + lane, fF);
      float e0 = (q == 0) ? r0.x : (q == 1) ? r0.y : (q == 2) ? r0.z : r0.w;
      float e1 = (q == 0) ? r1.x : (q == 1) ? r1.y : (q == 2) ? r1.z : r1.w;
      float e2 = (q == 0) ? r2.x : (q == 1) ? r2.y : (q == 2) ? r2.z : r2.w;
      float e3 = (q == 0) ? r3.x : (q == 1) ? r3.y : (q == 2) ? r3.z : r3.w;
      a0 += e0 * w; a1 += e1 * w; a2 += e2 * w; a3 += e3 * w;
    }
  }
  xw2[(long)(row0 + 0) * HID + lane] = a0;
  xw2[(long)(row0 + 1) * HID + lane] = a1;
  xw2[(long)(row0 + 2) * HID + lane] = a2;
  xw2[(long)(row0 + 3) * HID + lane] = a3;
}

// ---------- GCN aggregation via bucket gather ----------
__global__ __launch_bounds__(256) void gather_kernel(const float* __restrict__ xw,
                                                     const float* __restrict__ dinv,
                                                     const int* __restrict__ cnt,
                                                     const int* __restrict__ slot,
                                                     float* __restrict__ h,
                                                     float* __restrict__ n2,
                                                     const void* __restrict__ bias,
                                                     const int* __restrict__ flags,
                                                     int mode) {
  int n = blockIdx.x * 4 + (threadIdx.x >> 6);
  if (n >= NN) return;
  int c = threadIdx.x & 63;
  float dn = dinv[n];
  float acc = xw[(long)n * HID + c] * dn;      // self term
  int m = cnt[n]; if (m > CAP) m = CAP;
  const int* sl = slot + (long)n * CAP;
  for (int e0 = 0; e0 < m; e0 += 4) {
    int4 s4 = *(const int4*)(sl + e0);
    if (e0 + 0 < m) acc += xw[(long)s4.x * HID + c] * dinv[s4.x];
    if (e0 + 1 < m) acc += xw[(long)s4.y * HID + c] * dinv[s4.y];
    if (e0 + 2 < m) acc += xw[(long)s4.z * HID + c] * dinv[s4.z];
    if (e0 + 3 < m) acc += xw[(long)s4.w * HID + c] * dinv[s4.w];
  }
  acc *= dn;
  float b = ldf(bias, c, flags[0]);
  if (mode) {
    acc += b;
    acc = acc > 0.f ? acc : 0.f;
    h[(long)n * HID + c] = acc;
  } else {
    h[(long)n * HID + c] = acc;
    float v = acc + b;
    float s = v * v;
    s += __shfl_xor(s, 1); s += __shfl_xor(s, 2); s += __shfl_xor(s, 4);
    s += __shfl_xor(s, 8); s += __shfl_xor(s, 16); s += __shfl_xor(s, 32);
    if (c == 0) n2[n] = s;
  }
}

// ---------- FGW: 4 nodes/block, 8-lane octet per (node, template) ----------
#define NODES_PB 4
#define TPN 80            // threads per node (10 templates x 8 lanes)
#define XLP 65            // padded xl row stride

__global__ __launch_bounds__(320, 2) void fgw_kernel(
    const float* __restrict__ h2,        // [NN,64] fp32 ws (pre-b2)
    const void* __restrict__ b2v,
    const void* __restrict__ nbr_idx,
    const void* __restrict__ nbr_mask,
    const void* __restrict__ C_local,
    const void* __restrict__ tmpl,       // [10,8,8]
    const void* __restrict__ tfeat,      // [10,8,64]
    const void* __restrict__ Wlin,       // [74,6]
    const void* __restrict__ blin,       // [6]
    void* __restrict__ out,              // [NN,6]
    const int* __restrict__ flags,
    const float* __restrict__ tn2min,    // [11]: per-t mins + global min
    const float* __restrict__ n2)        // [NN] node norm^2
{
  const int tid = threadIdx.x;
  const int fF = flags[0];
  const int fI = flags[1];
  const int nb = tid / TPN;
  const int local = tid - nb * TPN;      // [0,80)
  const int t = local >> 3;
  const int j = local & 7;
  const int n = blockIdx.x * NODES_PB + nb;
  const int lane = tid & 63;
  const int ob = lane & 56;

  __shared__ float xlS[NODES_PB][LSZ][XLP];
  __shared__ float C1S[NODES_PB][81];
  __shared__ float hwS[NODES_PB][LSZ];
  __shared__ float f1S[NODES_PB][LSZ];
  __shared__ float xnS[NODES_PB][LSZ];
  __shared__ float distS[NODES_PB][NTPL];
  __shared__ float xmaxS[NODES_PB];
  __shared__ int   needS[NODES_PB];
  __shared__ int   sidxS[NODES_PB][LSZ];

  if (local < LSZ) {
    int idx = (local == 0) ? n : ldi(nbr_idx, (long)n * KNEI + local - 1, fI);
    sidxS[nb][local] = idx;
    xnS[nb][local] = n2[idx];
  }
  if (local < HID)
    xlS[nb][0][local] = h2[(long)n * HID + local] + ldf(b2v, local, fF);
  __syncthreads();   // B1

  if (local == 0) {
    float xm = xnS[nb][0];
#pragma unroll
    for (int l = 1; l < LSZ; ++l) xm = fmaxf(xm, xnS[nb][l]);
    xmaxS[nb] = xm;
    needS[nb] = ((sqrtf(tn2min[NTPL]) - sqrtf(xm)) >= 5.0990195f) ? 0 : 1;
  }
  __syncthreads();   // B2

  const int need = needS[nb];
  if (need) {
    for (int i = local; i < 8 * HID; i += TPN) {
      int l = 1 + (i >> 6), k = i & 63;
      xlS[nb][l][k] = h2[(long)sidxS[nb][l] * HID + k] + ldf(b2v, k, fF);
    }
    for (int i = local; i < 81; i += TPN)
      C1S[nb][i] = ldf(C_local, (long)n * 81 + i, fF);
  }
  __syncthreads();   // B3

  if (need && local < LSZ) {
    int l = local;
    float msum = 0.f, f1 = 0.f;
#pragma unroll
    for (int jj = 0; jj < LSZ; ++jj) {
      float mj = ldf(nbr_mask, (long)n * LSZ + jj, fF);
      msum += mj;
      float c = C1S[nb][l * LSZ + jj];
      f1 += c * c * mj;
    }
    float inv = frcp(msum);
    hwS[nb][l] = ldf(nbr_mask, (long)n * LSZ + l, fF) * inv;
    f1S[nb][l] = f1 * inv;
  }
  __syncthreads();   // B4

  bool slow = need && ((sqrtf(tn2min[t]) - sqrtf(xmaxS[nb])) < 5.0990195f);
  if (slow) {
    float C2c[NTN];
    float f2h2;
    {
      float s = 0.f;
#pragma unroll
      for (int m = 0; m < NTN; ++m) {
        C2c[m] = ldf(tmpl, t * 64 + m * 8 + j, fF);
        float r = ldf(tmpl, t * 64 + j * 8 + m, fF);
        s += r * r;
      }
      f2h2 = s * 0.125f;
    }
    float hwr[LSZ], f1r[LSZ];
#pragma unroll
    for (int l = 0; l < LSZ; ++l) { hwr[l] = hwS[nb][l]; f1r[l] = f1S[nb][l]; }

    float Mc[LSZ];
    {
      float accI[LSZ];
#pragma unroll
      for (int l = 0; l < LSZ; ++l) accI[l] = 0.f;
      float tn2 = 0.f;
      const long tb = (long)local * HID;
      for (int kb = 0; kb < 8; ++kb) {
        float r[8];
#pragma unroll
        for (int q = 0; q < 8; ++q) r[q] = ldf(tfeat, tb + kb * 8 + q, fF);
#pragma unroll
        for (int q = 0; q < 8; ++q) tn2 += r[q] * r[q];
#pragma unroll
        for (int l = 0; l < LSZ; ++l) {
          float s = 0.f;
#pragma unroll
          for (int q = 0; q < 8; ++q) s += xlS[nb][l][kb * 8 + q] * r[q];
          accI[l] += s;
        }
      }
#pragma unroll
      for (int l = 0; l < LSZ; ++l)
        Mc[l] = xnS[nb][l] + tn2 - 2.f * accI[l];
    }

    float Tc[LSZ], Kc[LSZ], u[LSZ];
#pragma unroll
    for (int l = 0; l < LSZ; ++l) Tc[l] = hwr[l] * 0.125f;

    float v = 1.0f;
    for (int outer = 0; outer < 3; ++outer) {
      float Ac[LSZ];
#pragma unroll
      for (int l = 0; l < LSZ; ++l) {
        float s = 0.f;
#pragma unroll
        for (int l2 = 0; l2 < LSZ; ++l2) s += C1S[nb][l * LSZ + l2] * Tc[l2];
        Ac[l] = s;
      }
#pragma unroll
      for (int l = 0; l < LSZ; ++l) {
        float s = 0.f;
#pragma unroll
        for (int m = 0; m < NTN; ++m) s += __shfl(Ac[l], ob + m) * C2c[m];
        float tens = f1r[l] + f2h2 - 2.f * s;
        Kc[l] = __expf(-5.0f * (Mc[l] + tens));
      }
      v = 1.0f;
      for (int it = 0; it < 5; ++it) {
#pragma unroll
        for (int l = 0; l < LSZ; ++l) {
          float p = Kc[l] * v;
          p += __shfl_xor(p, 1); p += __shfl_xor(p, 2); p += __shfl_xor(p, 4);
          u[l] = hwr[l] * frcp(p + 1e-16f);
        }
        float s = 0.f;
#pragma unroll
        for (int l = 0; l < LSZ; ++l) s += Kc[l] * u[l];
        v = 0.125f * frcp(s + 1e-16f);
      }
#pragma unroll
      for (int l = 0; l < LSZ; ++l) Tc[l] = u[l] * Kc[l] * v;
    }
    {
      float Ac[LSZ];
#pragma unroll
      for (int l = 0; l < LSZ; ++l) {
        float s = 0.f;
#pragma unroll
        for (int l2 = 0; l2 < LSZ; ++l2) s += C1S[nb][l * LSZ + l2] * Tc[l2];
        Ac[l] = s;
      }
      float cl = 0.f;
#pragma unroll
      for (int l = 0; l < LSZ; ++l) {
        float s = 0.f;
#pragma unroll
        for (int m = 0; m < NTN; ++m) s += __shfl(Ac[l], ob + m) * C2c[m];
        float tens = f1r[l] + f2h2 - 2.f * s;
        cl += Tc[l] * 0.5f * (Mc[l] + tens);
      }
      cl += __shfl_xor(cl, 1); cl += __shfl_xor(cl, 2); cl += __shfl_xor(cl, 4);
      if (j == 0) distS[nb][t] = cl;
    }
  } else if (j == 0) {
    distS[nb][t] = 0.f;
  }
  __syncthreads();   // B5

  if (local < NCLS) {
    int c = local;
    float acc = ldf(blin, c, fF);
#pragma unroll
    for (int k = 0; k < HID; ++k)
      acc += xlS[nb][0][k] * ldf(Wlin, k * NCLS + c, fF);
#pragma unroll
    for (int tt = 0; tt < NTPL; ++tt)
      acc += distS[nb][tt] * ldf(Wlin, (HID + tt) * NCLS + c, fF);
    float r = acc > 0.f ? acc : 0.f;
    if (fF) ((float*)out)[(long)n * NCLS + c] = r;
    else    ((bf16_t*)out)[(long)n * NCLS + c] = f2b(r);
  }
}

extern "C" void kernel_launch(void* const* d_in, const int* in_sizes, int n_in,
                              void* d_out, int out_size, void* d_ws, size_t ws_size,
                              hipStream_t stream) {
  (void)in_sizes; (void)n_in; (void)out_size; (void)ws_size;
  const void* x     = d_in[0];
  const void* ei    = d_in[1];
  const void* nbr   = d_in[2];
  const void* nmask = d_in[3];
  const void* Cl    = d_in[4];
  const void* W1    = d_in[5];
  const void* b1    = d_in[6];
  const void* W2    = d_in[7];
  const void* b2    = d_in[8];
  const void* tmpl  = d_in[9];
  const void* tfeat = d_in[10];
  const void* Wlin  = d_in[11];
  const void* blin  = d_in[12];

  // ws layout (4B words): flags[4] | tn2min[12] | dinv NN | n2 NN | pos NN |
  //                       slot CAP*NN | Wp 16K words (64KB) | bufA 64NN | bufB 64NN
  int*    flags  = (int*)d_ws;
  float*  tn2min = (float*)d_ws + 4;
  float*  dinv   = (float*)d_ws + 16;
  float*  n2     = dinv + NN;
  int*    pos    = (int*)(n2 + NN);
  int*    slot   = pos + NN;
  bf16_t* Wp     = (bf16_t*)(slot + (long)CAP * NN);
  float*  bufA   = (float*)((int*)Wp + 16384);
  float*  bufB   = bufA + (long)NN * HID;

  probe_kernel<<<1, 128, 0, stream>>>(x, ei, tfeat, flags, tn2min);
  wswz_kernel<<<128, 256, 0, stream>>>(W1, Wp, flags);

  hipMemsetAsync(pos, 0, NN * sizeof(int), stream);
  scatter_kernel<<<(EE + 255) / 256, 256, 0, stream>>>(ei, pos, slot, flags);
  dinv_kernel<<<(NN + 255) / 256, 256, 0, stream>>>(pos, dinv);

  // layer 1
  gemm1_kernel<<<NN / 16, 256, 0, stream>>>(x, Wp, W1, bufA, flags);
  gather_kernel<<<NN / 4, 256, 0, stream>>>(bufA, dinv, pos, slot, bufB,
                                            n2, b1, flags, 1);
  // layer 2 (n2 fused into this gather)
  gemm2_kernel<<<NN / 16, 256, 0, stream>>>(bufB, W2, bufA, flags);
  gather_kernel<<<NN / 4, 256, 0, stream>>>(bufA, dinv, pos, slot, bufB,
                                            n2, b2, flags, 0);

  fgw_kernel<<<NN / NODES_PB, 320, 0, stream>>>(bufB, b2, nbr, nmask, Cl, tmpl,
                                                tfeat, Wlin, blin, d_out, flags,
                                                tn2min, n2);
}

// Round 9
// 317.095 us; speedup vs baseline: 1.5342x; 1.2402x over previous
//
#include <hip/hip_runtime.h>

// OT_GNN: 2x GCN -> per-node fused-GW distance to 10 templates -> linear head.
// R9: gemm1 reverted to the empirically-best scalar form (R5, 110us; MFMA
// variants R6-R8 all lost to it). Fusions instead: gemm2 folded into gather1
// via in-wave shfl GEMV (h1 never hits memory), dinv computed inline from
// cnt, gather loads unrolled 8-deep, fgw epilogue weights staged to LDS.
// Certificate (R4): K = exp(-5(M+tens)) == 0 exactly in fp32 when
// (sqrt(tn2min)-sqrt(xn2max))^2 >= 26, since tens >= -2 => dist == 0 exact.

#define NN   20000
#define EE   320000
#define FIN  512
#define HID  64
#define KNEI 8
#define LSZ  9      // K_NEI + 1
#define NTPL 10
#define NTN  8
#define NCLS 6
#define CAP  48     // bucket capacity per node (max in-degree ~34)

typedef unsigned short bf16_t;
typedef unsigned short us8 __attribute__((ext_vector_type(8)));

__device__ __forceinline__ float b2f(bf16_t u) {
  union { unsigned int i; float f; } v; v.i = ((unsigned int)u) << 16; return v.f;
}
__device__ __forceinline__ bf16_t f2b(float f) {
  union { float f; unsigned int i; } v; v.f = f;
  unsigned int x = v.i;
  return (bf16_t)((x + 0x7fffu + ((x >> 16) & 1u)) >> 16);  // RNE
}
__device__ __forceinline__ float ldf(const void* p, long i, int fp32) {
  return fp32 ? ((const float*)p)[i] : b2f(((const bf16_t*)p)[i]);
}
__device__ __forceinline__ int ldi(const void* p, long i, int i64) {
  return i64 ? (int)((const long long*)p)[i] : ((const int*)p)[i];
}
__device__ __forceinline__ float frcp(float x) { return __builtin_amdgcn_rcpf(x); }

// ---------- dtype probe + template row-norm mins ----------
__global__ __launch_bounds__(128) void probe_kernel(const void* __restrict__ x,
                                                    const void* __restrict__ ei,
                                                    const void* __restrict__ tfeat,
                                                    int* __restrict__ flags,
                                                    float* __restrict__ tn2min) {
  __shared__ int sfl[2];
  __shared__ float tn2s[80];
  int tid = threadIdx.x;
  if (tid == 0) {
    int sane = 0;
    for (int k = 0; k < 64; k += 2) {
      bf16_t u = ((const bf16_t*)x)[k];
      int e = (u >> 7) & 0xff;
      if (e >= 112 && e <= 142) sane++;
    }
    int f0 = (sane < 24) ? 1 : 0;
    int zc = 0;
    for (int k = 1; k < 64; k += 2)
      if (((const int*)ei)[k] == 0) zc++;
    int f1 = (zc >= 16) ? 1 : 0;
    flags[0] = f0; flags[1] = f1;
    sfl[0] = f0; sfl[1] = f1;
  }
  __syncthreads();
  if (tid < 80) {
    int fF = sfl[0];
    float s = 0.f;
    for (int k = 0; k < HID; ++k) {
      float v = ldf(tfeat, (long)tid * HID + k, fF);
      s += v * v;
    }
    tn2s[tid] = s;
  }
  __syncthreads();
  if (tid == 0) {
    float gmin = 1e30f;
    for (int t = 0; t < NTPL; ++t) {
      float m = tn2s[t * 8];
      for (int r = 1; r < 8; ++r) m = fminf(m, tn2s[t * 8 + r]);
      tn2min[t] = m;
      gmin = fminf(gmin, m);
    }
    tn2min[NTPL] = gmin;
  }
}

// ---------- bucket scatter: pos becomes in-degree, slot holds sources -------
__global__ __launch_bounds__(256) void scatter_kernel(const void* __restrict__ ei,
                                                      int* __restrict__ pos,
                                                      int* __restrict__ slot,
                                                      const int* __restrict__ flags) {
  int i = blockIdx.x * 256 + threadIdx.x;
  if (i >= EE) return;
  int i64 = flags[1];
  int s = ldi(ei, i, i64);
  int d = ldi(ei, (long)EE + i, i64);
  int p = atomicAdd(&pos[d], 1);
  if (p < CAP) slot[d * CAP + p] = s;
}

// ---------- GEMM1 (scalar, R5 form): xw1 = x @ W1 ----------
__global__ __launch_bounds__(256) void gemm1_kernel(const void* __restrict__ x,
                                                    const void* __restrict__ W1,
                                                    float* __restrict__ xw1,
                                                    const int* __restrict__ flags) {
  int wave = blockIdx.x * 4 + (threadIdx.x >> 6);
  int lane = threadIdx.x & 63;
  int row0 = wave * 4;
  if (row0 >= NN) return;
  float a0 = 0.f, a1 = 0.f, a2 = 0.f, a3 = 0.f;
  if (!flags[0]) {
    const bf16_t* xb = (const bf16_t*)x + (long)row0 * FIN;
    const bf16_t* wp = (const bf16_t*)W1;
#pragma unroll 2
    for (int k8 = 0; k8 < FIN / 8; ++k8) {
      us8 r0 = *(const us8*)(xb + k8 * 8);
      us8 r1 = *(const us8*)(xb + FIN + k8 * 8);
      us8 r2 = *(const us8*)(xb + 2 * FIN + k8 * 8);
      us8 r3 = *(const us8*)(xb + 3 * FIN + k8 * 8);
#pragma unroll
      for (int q = 0; q < 8; ++q) {
        float w = b2f(wp[(k8 * 8 + q) * HID + lane]);
        a0 += b2f(r0[q]) * w;
        a1 += b2f(r1[q]) * w;
        a2 += b2f(r2[q]) * w;
        a3 += b2f(r3[q]) * w;
      }
    }
  } else {
    const float* x0 = (const float*)x + (long)row0 * FIN;
    const float* wp = (const float*)W1;
#pragma unroll 8
    for (int k = 0; k < FIN; ++k) {
      float w = wp[k * HID + lane];
      a0 += x0[k] * w;
      a1 += x0[FIN + k] * w;
      a2 += x0[2 * FIN + k] * w;
      a3 += x0[3 * FIN + k] * w;
    }
  }
  xw1[(long)(row0 + 0) * HID + lane] = a0;
  xw1[(long)(row0 + 1) * HID + lane] = a1;
  xw1[(long)(row0 + 2) * HID + lane] = a2;
  xw1[(long)(row0 + 3) * HID + lane] = a3;
}

// ---------- gather A: h1 = relu(Agg(xw1)+b1); xw2 = h1 @ W2 (in-wave GEMV) --
__global__ __launch_bounds__(256) void gatherA_kernel(const float* __restrict__ xw,
                                                      const int* __restrict__ cnt,
                                                      const int* __restrict__ slot,
                                                      float* __restrict__ xw2,
                                                      const void* __restrict__ b1v,
                                                      const void* __restrict__ W2,
                                                      const int* __restrict__ flags) {
  int n = blockIdx.x * 4 + (threadIdx.x >> 6);
  if (n >= NN) return;
  int fF = flags[0];
  int c = threadIdx.x & 63;
  float dn = rsqrtf((float)cnt[n] + 1.0f);
  float acc = xw[(long)n * HID + c] * dn;      // self term
  int m = cnt[n]; if (m > CAP) m = CAP;
  const int* sl = slot + (long)n * CAP;
  float accB = 0.f;
  for (int e0 = 0; e0 < m; e0 += 8) {
    int4 sa = *(const int4*)(sl + e0);
    int4 sb = *(const int4*)(sl + e0 + 4);
    if (e0 + 0 < m) acc  += xw[(long)sa.x * HID + c] * rsqrtf((float)cnt[sa.x] + 1.0f);
    if (e0 + 1 < m) accB += xw[(long)sa.y * HID + c] * rsqrtf((float)cnt[sa.y] + 1.0f);
    if (e0 + 2 < m) acc  += xw[(long)sa.z * HID + c] * rsqrtf((float)cnt[sa.z] + 1.0f);
    if (e0 + 3 < m) accB += xw[(long)sa.w * HID + c] * rsqrtf((float)cnt[sa.w] + 1.0f);
    if (e0 + 4 < m) acc  += xw[(long)sb.x * HID + c] * rsqrtf((float)cnt[sb.x] + 1.0f);
    if (e0 + 5 < m) accB += xw[(long)sb.y * HID + c] * rsqrtf((float)cnt[sb.y] + 1.0f);
    if (e0 + 6 < m) acc  += xw[(long)sb.z * HID + c] * rsqrtf((float)cnt[sb.z] + 1.0f);
    if (e0 + 7 < m) accB += xw[(long)sb.w * HID + c] * rsqrtf((float)cnt[sb.w] + 1.0f);
  }
  float h1 = (acc + accB) * dn + ldf(b1v, c, fF);
  h1 = h1 > 0.f ? h1 : 0.f;                     // relu'd hidden, channel c

  // xw2[n][c] = sum_k h1[k] * W2[k][c]  via 64 wave broadcasts
  float o = 0.f;
#pragma unroll 8
  for (int k = 0; k < HID; ++k)
    o += __shfl(h1, k) * ldf(W2, k * HID + c, fF);
  xw2[(long)n * HID + c] = o;
}

// ---------- gather B: h2 = Agg(xw2); n2 = ||h2+b2||^2 ----------
__global__ __launch_bounds__(256) void gatherB_kernel(const float* __restrict__ xw,
                                                      const int* __restrict__ cnt,
                                                      const int* __restrict__ slot,
                                                      float* __restrict__ h,
                                                      float* __restrict__ n2,
                                                      const void* __restrict__ b2v,
                                                      const int* __restrict__ flags) {
  int n = blockIdx.x * 4 + (threadIdx.x >> 6);
  if (n >= NN) return;
  int c = threadIdx.x & 63;
  float dn = rsqrtf((float)cnt[n] + 1.0f);
  float acc = xw[(long)n * HID + c] * dn;
  int m = cnt[n]; if (m > CAP) m = CAP;
  const int* sl = slot + (long)n * CAP;
  float accB = 0.f;
  for (int e0 = 0; e0 < m; e0 += 8) {
    int4 sa = *(const int4*)(sl + e0);
    int4 sb = *(const int4*)(sl + e0 + 4);
    if (e0 + 0 < m) acc  += xw[(long)sa.x * HID + c] * rsqrtf((float)cnt[sa.x] + 1.0f);
    if (e0 + 1 < m) accB += xw[(long)sa.y * HID + c] * rsqrtf((float)cnt[sa.y] + 1.0f);
    if (e0 + 2 < m) acc  += xw[(long)sa.z * HID + c] * rsqrtf((float)cnt[sa.z] + 1.0f);
    if (e0 + 3 < m) accB += xw[(long)sa.w * HID + c] * rsqrtf((float)cnt[sa.w] + 1.0f);
    if (e0 + 4 < m) acc  += xw[(long)sb.x * HID + c] * rsqrtf((float)cnt[sb.x] + 1.0f);
    if (e0 + 5 < m) accB += xw[(long)sb.y * HID + c] * rsqrtf((float)cnt[sb.y] + 1.0f);
    if (e0 + 6 < m) acc  += xw[(long)sb.z * HID + c] * rsqrtf((float)cnt[sb.z] + 1.0f);
    if (e0 + 7 < m) accB += xw[(long)sb.w * HID + c] * rsqrtf((float)cnt[sb.w] + 1.0f);
  }
  acc = (acc + accB) * dn;
  h[(long)n * HID + c] = acc;
  float v = acc + ldf(b2v, c, flags[0]);
  float s = v * v;
  s += __shfl_xor(s, 1); s += __shfl_xor(s, 2); s += __shfl_xor(s, 4);
  s += __shfl_xor(s, 8); s += __shfl_xor(s, 16); s += __shfl_xor(s, 32);
  if (c == 0) n2[n] = s;
}

// ---------- FGW: 4 nodes/block, 8-lane octet per (node, template) ----------
#define NODES_PB 4
#define TPN 80            // threads per node (10 templates x 8 lanes)
#define XLP 65            // padded xl row stride

__global__ __launch_bounds__(320, 2) void fgw_kernel(
    const float* __restrict__ h2,        // [NN,64] fp32 ws (pre-b2)
    const void* __restrict__ b2v,
    const void* __restrict__ nbr_idx,
    const void* __restrict__ nbr_mask,
    const void* __restrict__ C_local,
    const void* __restrict__ tmpl,       // [10,8,8]
    const void* __restrict__ tfeat,      // [10,8,64]
    const void* __restrict__ Wlin,       // [74,6]
    const void* __restrict__ blin,       // [6]
    void* __restrict__ out,              // [NN,6]
    const int* __restrict__ flags,
    const float* __restrict__ tn2min,    // [11]: per-t mins + global min
    const float* __restrict__ n2)        // [NN] node norm^2
{
  const int tid = threadIdx.x;
  const int fF = flags[0];
  const int fI = flags[1];
  const int nb = tid / TPN;
  const int local = tid - nb * TPN;      // [0,80)
  const int t = local >> 3;
  const int j = local & 7;
  const int n = blockIdx.x * NODES_PB + nb;
  const int lane = tid & 63;
  const int ob = lane & 56;

  __shared__ float xlS[NODES_PB][LSZ][XLP];
  __shared__ float C1S[NODES_PB][81];
  __shared__ float hwS[NODES_PB][LSZ];
  __shared__ float f1S[NODES_PB][LSZ];
  __shared__ float xnS[NODES_PB][LSZ];
  __shared__ float distS[NODES_PB][NTPL];
  __shared__ float xmaxS[NODES_PB];
  __shared__ int   needS[NODES_PB];
  __shared__ int   sidxS[NODES_PB][LSZ];
  __shared__ float WlinS[(HID + NTPL) * NCLS + NCLS];   // Wlin + blin

  // stage epilogue weights once per block (coalesced-ish)
  for (int i = tid; i < (HID + NTPL) * NCLS; i += 320)
    WlinS[i] = ldf(Wlin, i, fF);
  if (tid < NCLS) WlinS[(HID + NTPL) * NCLS + tid] = ldf(blin, tid, fF);

  if (local < LSZ) {
    int idx = (local == 0) ? n : ldi(nbr_idx, (long)n * KNEI + local - 1, fI);
    sidxS[nb][local] = idx;
    xnS[nb][local] = n2[idx];
  }
  if (local < HID)
    xlS[nb][0][local] = h2[(long)n * HID + local] + ldf(b2v, local, fF);
  __syncthreads();   // B1

  if (local == 0) {
    float xm = xnS[nb][0];
#pragma unroll
    for (int l = 1; l < LSZ; ++l) xm = fmaxf(xm, xnS[nb][l]);
    xmaxS[nb] = xm;
    needS[nb] = ((sqrtf(tn2min[NTPL]) - sqrtf(xm)) >= 5.0990195f) ? 0 : 1;
  }
  __syncthreads();   // B2

  const int need = needS[nb];
  if (need) {
    for (int i = local; i < 8 * HID; i += TPN) {
      int l = 1 + (i >> 6), k = i & 63;
      xlS[nb][l][k] = h2[(long)sidxS[nb][l] * HID + k] + ldf(b2v, k, fF);
    }
    for (int i = local; i < 81; i += TPN)
      C1S[nb][i] = ldf(C_local, (long)n * 81 + i, fF);
  }
  __syncthreads();   // B3

  if (need && local < LSZ) {
    int l = local;
    float msum = 0.f, f1 = 0.f;
#pragma unroll
    for (int jj = 0; jj < LSZ; ++jj) {
      float mj = ldf(nbr_mask, (long)n * LSZ + jj, fF);
      msum += mj;
      float c = C1S[nb][l * LSZ + jj];
      f1 += c * c * mj;
    }
    float inv = frcp(msum);
    hwS[nb][l] = ldf(nbr_mask, (long)n * LSZ + l, fF) * inv;
    f1S[nb][l] = f1 * inv;
  }
  __syncthreads();   // B4

  bool slow = need && ((sqrtf(tn2min[t]) - sqrtf(xmaxS[nb])) < 5.0990195f);
  if (slow) {
    float C2c[NTN];
    float f2h2;
    {
      float s = 0.f;
#pragma unroll
      for (int m = 0; m < NTN; ++m) {
        C2c[m] = ldf(tmpl, t * 64 + m * 8 + j, fF);
        float r = ldf(tmpl, t * 64 + j * 8 + m, fF);
        s += r * r;
      }
      f2h2 = s * 0.125f;
    }
    float hwr[LSZ], f1r[LSZ];
#pragma unroll
    for (int l = 0; l < LSZ; ++l) { hwr[l] = hwS[nb][l]; f1r[l] = f1S[nb][l]; }

    float Mc[LSZ];
    {
      float accI[LSZ];
#pragma unroll
      for (int l = 0; l < LSZ; ++l) accI[l] = 0.f;
      float tn2 = 0.f;
      const long tb = (long)local * HID;
      for (int kb = 0; kb < 8; ++kb) {
        float r[8];
#pragma unroll
        for (int q = 0; q < 8; ++q) r[q] = ldf(tfeat, tb + kb * 8 + q, fF);
#pragma unroll
        for (int q = 0; q < 8; ++q) tn2 += r[q] * r[q];
#pragma unroll
        for (int l = 0; l < LSZ; ++l) {
          float s = 0.f;
#pragma unroll
          for (int q = 0; q < 8; ++q) s += xlS[nb][l][kb * 8 + q] * r[q];
          accI[l] += s;
        }
      }
#pragma unroll
      for (int l = 0; l < LSZ; ++l)
        Mc[l] = xnS[nb][l] + tn2 - 2.f * accI[l];
    }

    float Tc[LSZ], Kc[LSZ], u[LSZ];
#pragma unroll
    for (int l = 0; l < LSZ; ++l) Tc[l] = hwr[l] * 0.125f;

    float v = 1.0f;
    for (int outer = 0; outer < 3; ++outer) {
      float Ac[LSZ];
#pragma unroll
      for (int l = 0; l < LSZ; ++l) {
        float s = 0.f;
#pragma unroll
        for (int l2 = 0; l2 < LSZ; ++l2) s += C1S[nb][l * LSZ + l2] * Tc[l2];
        Ac[l] = s;
      }
#pragma unroll
      for (int l = 0; l < LSZ; ++l) {
        float s = 0.f;
#pragma unroll
        for (int m = 0; m < NTN; ++m) s += __shfl(Ac[l], ob + m) * C2c[m];
        float tens = f1r[l] + f2h2 - 2.f * s;
        Kc[l] = __expf(-5.0f * (Mc[l] + tens));
      }
      v = 1.0f;
      for (int it = 0; it < 5; ++it) {
#pragma unroll
        for (int l = 0; l < LSZ; ++l) {
          float p = Kc[l] * v;
          p += __shfl_xor(p, 1); p += __shfl_xor(p, 2); p += __shfl_xor(p, 4);
          u[l] = hwr[l] * frcp(p + 1e-16f);
        }
        float s = 0.f;
#pragma unroll
        for (int l = 0; l < LSZ; ++l) s += Kc[l] * u[l];
        v = 0.125f * frcp(s + 1e-16f);
      }
#pragma unroll
      for (int l = 0; l < LSZ; ++l) Tc[l] = u[l] * Kc[l] * v;
    }
    {
      float Ac[LSZ];
#pragma unroll
      for (int l = 0; l < LSZ; ++l) {
        float s = 0.f;
#pragma unroll
        for (int l2 = 0; l2 < LSZ; ++l2) s += C1S[nb][l * LSZ + l2] * Tc[l2];
        Ac[l] = s;
      }
      float cl = 0.f;
#pragma unroll
      for (int l = 0; l < LSZ; ++l) {
        float s = 0.f;
#pragma unroll
        for (int m = 0; m < NTN; ++m) s += __shfl(Ac[l], ob + m) * C2c[m];
        float tens = f1r[l] + f2h2 - 2.f * s;
        cl += Tc[l] * 0.5f * (Mc[l] + tens);
      }
      cl += __shfl_xor(cl, 1); cl += __shfl_xor(cl, 2); cl += __shfl_xor(cl, 4);
      if (j == 0) distS[nb][t] = cl;
    }
  } else if (j == 0) {
    distS[nb][t] = 0.f;
  }
  __syncthreads();   // B5

  if (local < NCLS) {
    int c = local;
    float acc = WlinS[(HID + NTPL) * NCLS + c];
#pragma unroll
    for (int k = 0; k < HID; ++k)
      acc += xlS[nb][0][k] * WlinS[k * NCLS + c];
#pragma unroll
    for (int tt = 0; tt < NTPL; ++tt)
      acc += distS[nb][tt] * WlinS[(HID + tt) * NCLS + c];
    float r = acc > 0.f ? acc : 0.f;
    if (fF) ((float*)out)[(long)n * NCLS + c] = r;
    else    ((bf16_t*)out)[(long)n * NCLS + c] = f2b(r);
  }
}

extern "C" void kernel_launch(void* const* d_in, const int* in_sizes, int n_in,
                              void* d_out, int out_size, void* d_ws, size_t ws_size,
                              hipStream_t stream) {
  (void)in_sizes; (void)n_in; (void)out_size; (void)ws_size;
  const void* x     = d_in[0];
  const void* ei    = d_in[1];
  const void* nbr   = d_in[2];
  const void* nmask = d_in[3];
  const void* Cl    = d_in[4];
  const void* W1    = d_in[5];
  const void* b1    = d_in[6];
  const void* W2    = d_in[7];
  const void* b2    = d_in[8];
  const void* tmpl  = d_in[9];
  const void* tfeat = d_in[10];
  const void* Wlin  = d_in[11];
  const void* blin  = d_in[12];

  // ws layout (4B words): flags[4] | tn2min[12] | n2 NN | pos NN |
  //                       slot CAP*NN | bufA 64NN | bufB 64NN
  int*   flags  = (int*)d_ws;
  float* tn2min = (float*)d_ws + 4;
  float* n2     = (float*)d_ws + 16;
  int*   pos    = (int*)(n2 + NN);
  int*   slot   = pos + NN;
  float* bufA   = (float*)(slot + (long)CAP * NN);
  float* bufB   = bufA + (long)NN * HID;

  probe_kernel<<<1, 128, 0, stream>>>(x, ei, tfeat, flags, tn2min);

  hipMemsetAsync(pos, 0, NN * sizeof(int), stream);
  scatter_kernel<<<(EE + 255) / 256, 256, 0, stream>>>(ei, pos, slot, flags);

  // layer 1 GEMM
  gemm1_kernel<<<NN / 16, 256, 0, stream>>>(x, W1, bufA, flags);
  // gather A: aggregate xw1 -> relu(h1) -> in-wave GEMV with W2 -> xw2 (bufB)
  gatherA_kernel<<<NN / 4, 256, 0, stream>>>(bufA, pos, slot, bufB, b1, W2, flags);
  // gather B: aggregate xw2 -> h2 (bufA) + n2
  gatherB_kernel<<<NN / 4, 256, 0, stream>>>(bufB, pos, slot, bufA, n2, b2, flags);

  fgw_kernel<<<NN / NODES_PB, 320, 0, stream>>>(bufA, b2, nbr, nmask, Cl, tmpl,
                                                tfeat, Wlin, blin, d_out, flags,
                                                tn2min, n2);
}